// Round 6
// baseline (22.686 us; speedup 1.0000x reference)
//
#include <hip/hip_runtime.h>

// ECT: out[b,c,r,t] = sum_{n in (b,c)} sigmoid(SCALE*(lin[r] - x[n].v[:,t])), max-normalized per (b,c).
// Window+delta trick (validated r2-r4): sigmoid saturates within ~3 bins (SCALE=100, bin=2/63).
// Per point: deltas d0..d3 (window) + tail delta at 5 rows; inclusive prefix over r reconstructs.
// Fixed-point u32 accumulation in LDS (native ds_add_u32), merged across slices via global u64
// atomics (packed row-pairs, carry-free, bit-deterministic), fin kernel scans+normalizes.

constexpr int T   = 64;
constexpr int RES = 64;
constexpr float RADIUS = 1.0f;
constexpr float SCALE  = 100.0f;
constexpr float LOG2E  = 1.44269504088896340736f;

#define TPART   512            // part-kernel threads (8 waves)
#define NWAVE   8
#define NSLICE  2
#define ACCW    69             // acc row stride (69%32=5, odd -> 2/bank max, free)
#define TK      256            // table rows
#define FPSCALE 1048576.0f     // 2^20
#define FPQ     1048576u
#define FPINV   (1.0f / 1048576.0f)

__global__ __launch_bounds__(TPART) void ect_part(
    const float* __restrict__ x, const float* __restrict__ v,
    const int* __restrict__ index, const int* __restrict__ channels,
    unsigned long long* __restrict__ ws, int N)
{
  __shared__ unsigned acc[T * ACCW];              // [t][row 0..68], 17.3KB
  __shared__ alignas(16) unsigned tblD[TK * 4];   // window deltas d0..d3
  __shared__ unsigned tblE[TK];                   // tail delta
  __shared__ int l_bounds[2];

  const int blk  = blockIdx.x;
  const int seg  = blk >> 1;            // NSLICE == 2
  const int sl   = blk & 1;
  const int b    = seg >> 2;            // MAX_CHANNELS == 4
  const int c    = seg & 3;
  const int tid  = threadIdx.x;
  const int lane = tid & 63;
  const int wv   = tid >> 6;

  const float S2D  = SCALE * LOG2E * (2.0f * RADIUS / (RES - 1));
  const float invD = (RES - 1) / (2.0f * RADIUS);   // 31.5

  for (int i = tid; i < T * ACCW; i += TPART) acc[i] = 0u;

  // delta table: f=(q+0.5)/TK; s_u = fixed-point sigmoid at bin distance; d_u = s_u - s_{u-1}
  for (int i = tid; i < TK * 5; i += TPART) {
    const int   q = i / 5, u = i - q * 5;
    const float f = (q + 0.5f) * (1.0f / TK);
    unsigned qcur, qprev = 0u;
    {
      float e = __builtin_amdgcn_exp2f(S2D * (1.0f + f - (float)min(u, 3)));
      qcur = (unsigned)(FPSCALE / (1.0f + e) + 0.5f);
    }
    if (u > 0) {
      float e = __builtin_amdgcn_exp2f(S2D * (1.0f + f - (float)(min(u, 4) - 1)));
      qprev = (unsigned)(FPSCALE / (1.0f + e) + 0.5f);
    }
    if (u < 4) tblD[q * 4 + u] = qcur - qprev;
    else       tblE[q]         = FPQ - qprev;
  }

  // wave-parallel 64-ary search for batch bounds (waves 6,7)
  if (wv >= 6) {
    const int tg = b + (wv - 6);
    int lo = 0, len = N;
    while (len > 64) {
      int step = (len + 63) >> 6;
      int p = lo + lane * step;
      bool lt = (p < lo + len) && (index[p] < tg);
      unsigned long long mask = __ballot(lt);
      if (mask) lo += (63 - __clzll(mask)) * step + 1;
      len = min(step, N - lo);
    }
    int p = lo + lane;
    bool ge = (lane < len) && (index[p] >= tg);
    unsigned long long mask = __ballot(ge);
    int ans = mask ? (lo + (int)__builtin_ctzll(mask)) : (lo + len);
    if (lane == 0) l_bounds[wv - 6] = ans;
  }
  __syncthreads();

  const int s0  = l_bounds[0], s1 = l_bounds[1];
  const int len = s1 - s0;
  const int p0  = s0 + (len * sl) / NSLICE;
  const int p1  = s0 + (len * (sl + 1)) / NSLICE;

  // per-lane direction t = lane; fold invD into weights
  const float w0 = v[0 * T + lane] * invD;
  const float w1 = v[1 * T + lane] * invD;
  const float w2 = v[2 * T + lane] * invD;
  unsigned* const arow0 = &acc[lane * ACCW];

  for (int gb = p0 + wv * 64; gb < p1; gb += NWAVE * 64) {
    const int  pt    = gb + lane;
    const bool valid = pt < p1;
    int   ch = -1;
    float px = 0.f, py = 0.f, pz = 0.f;
    if (valid) {
      ch = channels[pt];
      px = x[pt * 3 + 0];
      py = x[pt * 3 + 1];
      pz = x[pt * 3 + 2];
    }
    unsigned long long mask = __ballot(ch == c);
    if (!mask) continue;

    // 2-deep pipelined bit-walk: issue next point's table read before current atomics
    int j = (int)__builtin_ctzll(mask); mask &= mask - 1;
    float qx = __int_as_float(__builtin_amdgcn_readlane(__float_as_int(px), j));
    float qy = __int_as_float(__builtin_amdgcn_readlane(__float_as_int(py), j));
    float qz = __int_as_float(__builtin_amdgcn_readlane(__float_as_int(pz), j));
    float g  = fmaf(qx, w0, fmaf(qy, w1, fmaf(qz, w2, invD)));
    float gf = floorf(g);
    int   fq = min((int)((g - gf) * (float)TK), TK - 1);
    int   loc = min(max((int)gf - 1, -4), 64);
    uint4    tv = *(const uint4*)&tblD[fq << 2];
    unsigned te = tblE[fq];

    while (true) {
      uint4 tvn; unsigned ten = 0u; int locn = 0;
      const bool more = (mask != 0ull);
      if (more) {
        int j2 = (int)__builtin_ctzll(mask); mask &= mask - 1;
        float ax = __int_as_float(__builtin_amdgcn_readlane(__float_as_int(px), j2));
        float ay = __int_as_float(__builtin_amdgcn_readlane(__float_as_int(py), j2));
        float az = __int_as_float(__builtin_amdgcn_readlane(__float_as_int(pz), j2));
        float g2  = fmaf(ax, w0, fmaf(ay, w1, fmaf(az, w2, invD)));
        float gf2 = floorf(g2);
        int   fq2 = min((int)((g2 - gf2) * (float)TK), TK - 1);
        locn = min(max((int)gf2 - 1, -4), 64);
        tvn = *(const uint4*)&tblD[fq2 << 2];
        ten = tblE[fq2];
      }
      atomicAdd(&arow0[max(loc + 0, 0)], tv.x);
      atomicAdd(&arow0[max(loc + 1, 0)], tv.y);
      atomicAdd(&arow0[max(loc + 2, 0)], tv.z);
      atomicAdd(&arow0[max(loc + 3, 0)], tv.w);
      atomicAdd(&arow0[max(loc + 4, 0)], te);
      if (!more) break;
      tv = tvn; te = ten; loc = locn;
    }
  }
  __syncthreads();

  // flush rows 0..63 as packed u64 row-pairs via global atomics (carry-free: cell < 2^32)
  unsigned long long* const wseg = ws + (size_t)seg * (T * 32);
  for (int i = tid; i < T * 32; i += TPART) {
    const int t = i >> 5, rp = i & 31;
    const unsigned lo32 = acc[t * ACCW + 2 * rp];
    const unsigned hi32 = acc[t * ACCW + 2 * rp + 1];
    const unsigned long long val = (unsigned long long)lo32 | ((unsigned long long)hi32 << 32);
    if (val) atomicAdd(&wseg[i], val);
  }
}

__global__ __launch_bounds__(1024) void ect_fin(
    const unsigned* __restrict__ ws, float* __restrict__ out)
{
  __shared__ float fin[RES * 65];
  __shared__ float wmax[16];
  __shared__ float s_scale;
  const int seg  = blockIdx.x;
  const int tid  = threadIdx.x;
  const int lane = tid & 63;
  const int wv   = tid >> 6;
  const unsigned* const wsg = ws + (size_t)seg * (T * RES);

  #pragma unroll
  for (int u2 = 0; u2 < 4; ++u2) {
    const int t = (wv << 2) | u2;
    unsigned h = wsg[t * 64 + lane];               // lane = r
    #pragma unroll
    for (int d = 1; d < 64; d <<= 1) {
      unsigned o = __shfl_up(h, (unsigned)d);
      if (lane >= d) h += o;
    }
    fin[lane * 65 + t] = (float)h * FPINV;
  }
  __syncthreads();

  float vals[4];
  float mx = 0.0f;
  #pragma unroll
  for (int k = 0; k < 4; ++k) {
    const int r = wv + k * 16;                     // flat = tid + k*1024 -> r, t = lane
    vals[k] = fin[r * 65 + lane];
    mx = fmaxf(mx, vals[k]);
  }
  #pragma unroll
  for (int s = 32; s >= 1; s >>= 1) mx = fmaxf(mx, __shfl_xor(mx, s));
  if (lane == 0) wmax[wv] = mx;
  __syncthreads();
  if (tid == 0) {
    float m2 = wmax[0];
    #pragma unroll
    for (int i = 1; i < 16; ++i) m2 = fmaxf(m2, wmax[i]);
    s_scale = (m2 > 0.0f) ? 1.0f / m2 : 1.0f;
  }
  __syncthreads();
  const float sc = s_scale;
  float* const o = out + (size_t)seg * (RES * T);
  #pragma unroll
  for (int k = 0; k < 4; ++k) o[tid + k * 1024] = vals[k] * sc;
}

extern "C" void kernel_launch(void* const* d_in, const int* in_sizes, int n_in,
                              void* d_out, int out_size, void* d_ws, size_t ws_size,
                              hipStream_t stream) {
  const float* x        = (const float*)d_in[0];
  const float* v        = (const float*)d_in[1];
  const int*   index    = (const int*)d_in[2];
  const int*   channels = (const int*)d_in[3];
  float*       out      = (float*)d_out;
  const int N    = in_sizes[2];              // 32768
  const int nseg = out_size / (RES * T);     // 128

  hipMemsetAsync(d_ws, 0, (size_t)nseg * RES * T * sizeof(unsigned), stream);
  hipLaunchKernelGGL(ect_part, dim3(nseg * NSLICE), dim3(TPART), 0, stream,
                     x, v, index, channels, (unsigned long long*)d_ws, N);
  hipLaunchKernelGGL(ect_fin, dim3(nseg), dim3(1024), 0, stream,
                     (const unsigned*)d_ws, out);
}